// Round 2
// baseline (923.075 us; speedup 1.0000x reference)
//
#include <hip/hip_runtime.h>

#define T_STEPS 256
#define B_SZ    128
#define F_SZ    2500
#define H_SZ    128
#define O_SZ    2

// ---------------- K1: transpose W1 [H][F] -> W1T [F][H] ----------------
__global__ __launch_bounds__(256) void k_transpose(const float* __restrict__ W1,
                                                   float* __restrict__ W1T) {
    int idx = blockIdx.x * 256 + threadIdx.x;   // 320000 total
    if (idx >= F_SZ * H_SZ) return;
    int k = idx >> 7;       // F index
    int h = idx & 127;      // H index
    W1T[idx] = W1[h * F_SZ + k];
}

// ---------------- K2: cur1[t][b][h] = x[b][t][:] . W1[h][:] + b1[h] ----------------
// fp32 inputs, fp64 accumulation (decision-critical: LIF threshold crossings must
// match the fp64 numpy reference; fp32 accumulation flips borderline spikes).
// One workgroup per t (256 WGs, 1 per CU). Tile: 128 (b) x 128 (h), K_blk = 32.
__global__ __launch_bounds__(256, 1) void k_gemm(const float* __restrict__ x,
                                                 const float* __restrict__ W1T,
                                                 const float* __restrict__ b1g,
                                                 double* __restrict__ cur1) {
    __shared__ float Alds[32 * 128];
    __shared__ float Blds[32 * 128];

    const int t    = blockIdx.x;
    const int tid  = threadIdx.x;
    const int lane = tid & 63;
    const int w    = tid >> 6;
    const int wm   = w >> 1;        // row half (0..1)
    const int wn   = w & 1;         // col half (0..1)
    const int li   = lane & 7;      // row group within wave
    const int lj   = lane >> 3;     // col group within wave

    // staging assignments
    const int ac = tid & 7;         // A k-chunk (4 floats)
    const int ar = tid >> 3;        // A row 0..31 (+32*i)
    const int bn = tid & 31;        // B n-chunk (4 floats)
    const int bk = tid >> 5;        // B k row 0..7 (+8*i)

    float4 aV[4], bV[4];

    auto loadA = [&](int k0) {
        const int k = k0 + ac * 4;
        const bool ok = (k < F_SZ);
        #pragma unroll
        for (int i = 0; i < 4; ++i) {
            const int rr = ar + i * 32;           // b index
            if (ok) aV[i] = *(const float4*)(x + (size_t)(rr * T_STEPS + t) * F_SZ + k);
            else    aV[i] = make_float4(0.f, 0.f, 0.f, 0.f);
        }
    };
    auto loadB = [&](int k0) {
        #pragma unroll
        for (int i = 0; i < 4; ++i) {
            const int k = k0 + bk + i * 8;
            if (k < F_SZ) bV[i] = *(const float4*)(W1T + k * H_SZ + bn * 4);
            else          bV[i] = make_float4(0.f, 0.f, 0.f, 0.f);
        }
    };
    auto storeTiles = [&]() {
        #pragma unroll
        for (int i = 0; i < 4; ++i) {
            const int rr = ar + i * 32;
            Alds[(ac * 4 + 0) * 128 + rr] = aV[i].x;
            Alds[(ac * 4 + 1) * 128 + rr] = aV[i].y;
            Alds[(ac * 4 + 2) * 128 + rr] = aV[i].z;
            Alds[(ac * 4 + 3) * 128 + rr] = aV[i].w;
            *(float4*)(Blds + (bk + i * 8) * 128 + bn * 4) = bV[i];
        }
    };

    double acc[2][2][4][4];
    #pragma unroll
    for (int a = 0; a < 2; ++a)
        #pragma unroll
        for (int b = 0; b < 2; ++b)
            #pragma unroll
            for (int i = 0; i < 4; ++i)
                #pragma unroll
                for (int j = 0; j < 4; ++j)
                    acc[a][b][i][j] = 0.0;

    const int NSTEP = (F_SZ + 31) / 32;   // 79
    loadA(0);
    loadB(0);

    #pragma unroll 1
    for (int s = 0; s < NSTEP; ++s) {
        __syncthreads();                  // previous compute done, LDS reusable
        storeTiles();
        if (s + 1 < NSTEP) { loadA((s + 1) * 32); loadB((s + 1) * 32); }  // prefetch
        __syncthreads();                  // tiles visible

        const float* Ab = Alds + wm * 64 + li * 4;
        const float* Bb = Blds + wn * 64 + lj * 4;
        #pragma unroll
        for (int k = 0; k < 32; ++k) {
            const float4 a0  = *(const float4*)(Ab + k * 128);
            const float4 a1  = *(const float4*)(Ab + k * 128 + 32);
            const float4 bb0 = *(const float4*)(Bb + k * 128);
            const float4 bb1 = *(const float4*)(Bb + k * 128 + 32);
            const double av[2][4] = {{a0.x, a0.y, a0.z, a0.w}, {a1.x, a1.y, a1.z, a1.w}};
            const double bv[2][4] = {{bb0.x, bb0.y, bb0.z, bb0.w}, {bb1.x, bb1.y, bb1.z, bb1.w}};
            #pragma unroll
            for (int rh = 0; rh < 2; ++rh)
                #pragma unroll
                for (int i = 0; i < 4; ++i)
                    #pragma unroll
                    for (int ch = 0; ch < 2; ++ch)
                        #pragma unroll
                        for (int j = 0; j < 4; ++j)
                            acc[rh][ch][i][j] = fma(av[rh][i], bv[ch][j], acc[rh][ch][i][j]);
        }
    }

    // epilogue: add bias (fp64), store doubles
    const float4 bias0 = *(const float4*)(b1g + wn * 64 + lj * 4);
    const float4 bias1 = *(const float4*)(b1g + wn * 64 + lj * 4 + 32);
    const double bias[2][4] = {{bias0.x, bias0.y, bias0.z, bias0.w},
                               {bias1.x, bias1.y, bias1.z, bias1.w}};
    #pragma unroll
    for (int rh = 0; rh < 2; ++rh) {
        #pragma unroll
        for (int i = 0; i < 4; ++i) {
            const int r = wm * 64 + li * 4 + rh * 32 + i;   // b index
            double* outp = cur1 + (size_t)(t * 128 + r) * 128 + wn * 64 + lj * 4;
            #pragma unroll
            for (int j = 0; j < 4; ++j) {
                outp[j]      = acc[rh][0][i][j] + bias[0][j];
                outp[j + 32] = acc[rh][1][i][j] + bias[1][j];
            }
        }
    }
}

// ---------------- K3: LIF layer 1 (fp64), cur1 (double) -> spk1 (float 0/1) ----------------
// One thread per (b,h); sequential over t. index: t*16384 + (b*128+h).
__global__ __launch_bounds__(256) void k_lif1(const double* __restrict__ cur1,
                                              float* __restrict__ spk1) {
    const int tid = blockIdx.x * 256 + threadIdx.x;   // 0..16383
    double mem = 0.0;
    #pragma unroll 4
    for (int t = 0; t < T_STEPS; ++t) {
        const double cur = cur1[t * 16384 + tid];
        const double rst = (mem > 1.0) ? 1.0 : 0.0;   // spike of OLD mem
        mem = 0.9 * mem + cur - rst;
        spk1[t * 16384 + tid] = (mem > 1.0) ? 1.0f : 0.0f;
    }
}

// ---------------- K4: cur2[t][b][o] = spk1[t][b][:] . W2[o][:] + b2[o] (fp64) ----------------
// One wave per (t,b) pair. Spikes are exact 0/1; products fp32*fp32 exact in fp64.
__global__ __launch_bounds__(256) void k_cur2(const float* __restrict__ spk1,
                                              const float* __restrict__ W2,
                                              const float* __restrict__ b2,
                                              double* __restrict__ cur2) {
    const int wave = (blockIdx.x * 256 + threadIdx.x) >> 6;  // 0..32767 = t*128+b
    const int lane = threadIdx.x & 63;
    const float2 s  = *(const float2*)(spk1 + (size_t)wave * 128 + lane * 2);
    const float2 w0 = *(const float2*)(W2 + lane * 2);
    const float2 w1 = *(const float2*)(W2 + 128 + lane * 2);
    double v0 = (double)s.x * (double)w0.x + (double)s.y * (double)w0.y;
    double v1 = (double)s.x * (double)w1.x + (double)s.y * (double)w1.y;
    #pragma unroll
    for (int off = 32; off >= 1; off >>= 1) {
        v0 += __shfl_down(v0, off);
        v1 += __shfl_down(v1, off);
    }
    if (lane == 0) {
        cur2[wave * 2 + 0] = v0 + (double)b2[0];
        cur2[wave * 2 + 1] = v1 + (double)b2[1];
    }
}

// ---------------- K5: LIF layer 2 (fp64) + write fp32 outputs ----------------
// 256 threads: tid = b*2 + o. Outputs: spk [0..65535], mem [65536..131071].
__global__ __launch_bounds__(256) void k_lif2(const double* __restrict__ cur2,
                                              float* __restrict__ out) {
    const int tid = threadIdx.x;
    double mem = 0.0;
    float* spk_out = out;
    float* mem_out = out + T_STEPS * B_SZ * O_SZ;
    #pragma unroll 4
    for (int t = 0; t < T_STEPS; ++t) {
        const double cur = cur2[t * 256 + tid];
        const double rst = (mem > 1.0) ? 1.0 : 0.0;
        mem = 0.9 * mem + cur - rst;
        spk_out[t * 256 + tid] = (mem > 1.0) ? 1.0f : 0.0f;
        mem_out[t * 256 + tid] = (float)mem;
    }
}

extern "C" void kernel_launch(void* const* d_in, const int* in_sizes, int n_in,
                              void* d_out, int out_size, void* d_ws, size_t ws_size,
                              hipStream_t stream) {
    const float* x  = (const float*)d_in[0];   // [128][256][2500]
    const float* W1 = (const float*)d_in[1];   // [128][2500]
    const float* b1 = (const float*)d_in[2];   // [128]
    const float* W2 = (const float*)d_in[3];   // [2][128]
    const float* b2 = (const float*)d_in[4];   // [2]
    float* out = (float*)d_out;                // 131072 floats

    char* ws = (char*)d_ws;
    double* cur1 = (double*)ws;                                   // 32768*128*8 = 33,554,432 B
    float*  spk1 = (float*)(ws + 33554432);                       // 32768*128*4 = 16,777,216 B
    float*  W1T  = (float*)(ws + 33554432 + 16777216);            // 2500*128*4  =  1,280,000 B
    double* cur2 = (double*)(ws + 33554432 + 16777216 + 1280000); // 32768*2*8   =    524,288 B

    k_transpose<<<1250, 256, 0, stream>>>(W1, W1T);
    k_gemm<<<256, 256, 0, stream>>>(x, W1T, b1, cur1);
    k_lif1<<<64, 256, 0, stream>>>(cur1, spk1);
    k_cur2<<<8192, 256, 0, stream>>>(spk1, W2, b2, cur2);
    k_lif2<<<1, 256, 0, stream>>>(cur2, out);
}